// Round 1
// baseline (12363.854 us; speedup 1.0000x reference)
//
#include <hip/hip_runtime.h>

// GAT 2-layer GNN, N=100000 nodes, E=3200000 edges (+N self-loops), H=32.
// All f32. Strategy: edge-parallel passes with atomics; per-edge attention
// scalar uses ea . (We @ a_edge) (4-dot) instead of materializing E x 32.

#define NN 100000
#define EE 3200000
#define ET (EE + NN)
#define SLOPE 0.2f

// monotone float <-> uint encoding for atomicMax on floats
__device__ __forceinline__ unsigned fenc(float f) {
    unsigned b = __float_as_uint(f);
    return (b & 0x80000000u) ? ~b : (b | 0x80000000u);
}
__device__ __forceinline__ float fdec(unsigned u) {
    unsigned b = (u & 0x80000000u) ? (u & 0x7FFFFFFFu) : ~u;
    return __uint_as_float(b);
}

__global__ void k_loop_stats(const int* __restrict__ ei, const float* __restrict__ ea,
                             float* __restrict__ cnt, float* __restrict__ lsum) {
    int e = blockIdx.x * blockDim.x + threadIdx.x;
    if (e >= EE) return;
    int d = ei[EE + e];
    float4 a = reinterpret_cast<const float4*>(ea)[e];
    atomicAdd(&cnt[d], 1.0f);
    atomicAdd(&lsum[d * 4 + 0], a.x);
    atomicAdd(&lsum[d * 4 + 1], a.y);
    atomicAdd(&lsum[d * 4 + 2], a.z);
    atomicAdd(&lsum[d * 4 + 3], a.w);
}

__global__ void k_loop_fin(float* __restrict__ lsum, const float* __restrict__ cnt) {
    int n = blockIdx.x * blockDim.x + threadIdx.x;
    if (n >= NN) return;
    float inv = 1.0f / fmaxf(cnt[n], 1.0f);
    float4 a = reinterpret_cast<float4*>(lsum)[n];
    a.x *= inv; a.y *= inv; a.z *= inv; a.w *= inv;
    reinterpret_cast<float4*>(lsum)[n] = a;
}

// w4[0..3] = We1 @ a_edge1 ; w4[4..7] = We2 @ a_edge2
__global__ void k_small(const float* __restrict__ We1, const float* __restrict__ ae1,
                        const float* __restrict__ We2, const float* __restrict__ ae2,
                        float* __restrict__ w4) {
    int t = threadIdx.x;
    if (t < 4) {
        float s = 0.f;
        for (int k = 0; k < 32; k++) s += We1[t * 32 + k] * ae1[k];
        w4[t] = s;
    } else if (t < 8) {
        float s = 0.f;
        for (int k = 0; k < 32; k++) s += We2[(t - 4) * 32 + k] * ae2[k];
        w4[t] = s;
    }
}

// h = x @ W1 (N x 3 -> N x 32), plus hs = h.a_src, hd = h.a_dst
__global__ void k_h1(const float* __restrict__ x, const float* __restrict__ W,
                     const float* __restrict__ as_, const float* __restrict__ ad_,
                     float* __restrict__ h, float* __restrict__ hs, float* __restrict__ hd) {
    __shared__ float sW[96], sa[32], sd[32];
    int t = threadIdx.x;
    if (t < 96) sW[t] = W[t];
    if (t < 32) { sa[t] = as_[t]; sd[t] = ad_[t]; }
    __syncthreads();
    int n = blockIdx.x * blockDim.x + t;
    if (n >= NN) return;
    float x0 = x[n * 3 + 0], x1 = x[n * 3 + 1], x2 = x[n * 3 + 2];
    float ss = 0.f, dd = 0.f;
    float* hp = h + (size_t)n * 32;
#pragma unroll
    for (int q = 0; q < 8; q++) {
        float4 o;
        float* op = (float*)&o;
#pragma unroll
        for (int j = 0; j < 4; j++) {
            int k = q * 4 + j;
            float v = x0 * sW[k] + x1 * sW[32 + k] + x2 * sW[64 + k];
            op[j] = v;
            ss += v * sa[k];
            dd += v * sd[k];
        }
        reinterpret_cast<float4*>(hp)[q] = o;
    }
    hs[n] = ss; hd[n] = dd;
}

// h = x2 @ W2 (N x 32 -> N x 32) + dots
__global__ void k_h2(const float* __restrict__ x2, const float* __restrict__ W,
                     const float* __restrict__ as_, const float* __restrict__ ad_,
                     float* __restrict__ h, float* __restrict__ hs, float* __restrict__ hd) {
    __shared__ float sW[1024], sa[32], sd[32];
    int t = threadIdx.x;
    for (int i = t; i < 1024; i += blockDim.x) sW[i] = W[i];
    if (t < 32) { sa[t] = as_[t]; sd[t] = ad_[t]; }
    __syncthreads();
    int n = blockIdx.x * blockDim.x + t;
    if (n >= NN) return;
    float xl[32];
    const float4* xp = reinterpret_cast<const float4*>(x2 + (size_t)n * 32);
#pragma unroll
    for (int q = 0; q < 8; q++) {
        float4 v = xp[q];
        xl[q * 4 + 0] = v.x; xl[q * 4 + 1] = v.y; xl[q * 4 + 2] = v.z; xl[q * 4 + 3] = v.w;
    }
    float ss = 0.f, dd = 0.f;
    float* hp = h + (size_t)n * 32;
    for (int q = 0; q < 8; q++) {
        float4 o;
        float* op = (float*)&o;
        for (int j = 0; j < 4; j++) {
            int k = q * 4 + j;
            float acc = 0.f;
#pragma unroll
            for (int i = 0; i < 32; i++) acc += xl[i] * sW[i * 32 + k];
            op[j] = acc;
            ss += acc * sa[k];
            dd += acc * sd[k];
        }
        reinterpret_cast<float4*>(hp)[q] = o;
    }
    hs[n] = ss; hd[n] = dd;
}

// pass A: per-edge logit + segment max over dst
__global__ void k_edge_logits(const int* __restrict__ ei, const float* __restrict__ ea,
                              const float* __restrict__ lattr,
                              const float* __restrict__ hs, const float* __restrict__ hd,
                              const float* __restrict__ w4,
                              float* __restrict__ logits, unsigned* __restrict__ mmax) {
    int e = blockIdx.x * blockDim.x + threadIdx.x;
    if (e >= ET) return;
    int s, d; float4 a;
    if (e < EE) {
        s = ei[e]; d = ei[EE + e];
        a = reinterpret_cast<const float4*>(ea)[e];
    } else {
        s = d = e - EE;
        a = reinterpret_cast<const float4*>(lattr)[s];
    }
    float l = hs[s] + hd[d] + a.x * w4[0] + a.y * w4[1] + a.z * w4[2] + a.w * w4[3];
    l = (l >= 0.0f) ? l : SLOPE * l;
    logits[e] = l;
    atomicMax(&mmax[d], fenc(l));
}

// pass B: w = exp(l - m[dst]); denom += w; accum[dst] += w * h[src]
__global__ void k_edge_accum(const int* __restrict__ ei, const float* __restrict__ logits,
                             const unsigned* __restrict__ mmax, const float* __restrict__ h,
                             float* __restrict__ denom, float* __restrict__ accum) {
    int e = blockIdx.x * blockDim.x + threadIdx.x;
    if (e >= ET) return;
    int s, d;
    if (e < EE) { s = ei[e]; d = ei[EE + e]; }
    else { s = d = e - EE; }
    float w = expf(logits[e] - fdec(mmax[d]));
    atomicAdd(&denom[d], w);
    const float4* hp = reinterpret_cast<const float4*>(h + (size_t)s * 32);
    float* ap = accum + (size_t)d * 32;
#pragma unroll
    for (int q = 0; q < 8; q++) {
        float4 v = hp[q];
        atomicAdd(&ap[q * 4 + 0], w * v.x);
        atomicAdd(&ap[q * 4 + 1], w * v.y);
        atomicAdd(&ap[q * 4 + 2], w * v.z);
        atomicAdd(&ap[q * 4 + 3], w * v.w);
    }
}

template <int RELU>
__global__ void k_finalize(const float* __restrict__ accum, const float* __restrict__ denom,
                           const float* __restrict__ b, float* __restrict__ out) {
    int idx = blockIdx.x * blockDim.x + threadIdx.x;
    if (idx >= NN * 8) return;
    int n = idx >> 3, q = idx & 7;
    float inv = 1.0f / denom[n];
    float4 a = reinterpret_cast<const float4*>(accum)[idx];
    float4 bb = reinterpret_cast<const float4*>(b)[q];
    float4 o;
    o.x = a.x * inv + bb.x;
    o.y = a.y * inv + bb.y;
    o.z = a.z * inv + bb.z;
    o.w = a.w * inv + bb.w;
    if (RELU) {
        o.x = fmaxf(o.x, 0.f); o.y = fmaxf(o.y, 0.f);
        o.z = fmaxf(o.z, 0.f); o.w = fmaxf(o.w, 0.f);
    }
    reinterpret_cast<float4*>(out)[idx] = o;
}

__global__ void k_final(const float* __restrict__ h2, const float* __restrict__ Wl,
                        const float* __restrict__ bl, float* __restrict__ y) {
    __shared__ float sW[32];
    __shared__ float sb;
    int t = threadIdx.x;
    if (t < 32) sW[t] = Wl[t];
    if (t == 0) sb = bl[0];
    __syncthreads();
    int n = blockIdx.x * blockDim.x + t;
    if (n >= NN) return;
    const float4* hp = reinterpret_cast<const float4*>(h2 + (size_t)n * 32);
    float acc = 0.f;
#pragma unroll
    for (int q = 0; q < 8; q++) {
        float4 v = hp[q];
        acc += v.x * sW[q * 4 + 0] + v.y * sW[q * 4 + 1] + v.z * sW[q * 4 + 2] + v.w * sW[q * 4 + 3];
    }
    y[n] = fmaxf(acc + sb, 0.0f);
}

extern "C" void kernel_launch(void* const* d_in, const int* in_sizes, int n_in,
                              void* d_out, int out_size, void* d_ws, size_t ws_size,
                              hipStream_t stream) {
    const float* x   = (const float*)d_in[0];
    const int*   ei  = (const int*)d_in[1];
    const float* ea  = (const float*)d_in[2];
    const float* W1  = (const float*)d_in[3];
    const float* We1 = (const float*)d_in[4];
    const float* as1 = (const float*)d_in[5];
    const float* ad1 = (const float*)d_in[6];
    const float* ae1 = (const float*)d_in[7];
    const float* b1  = (const float*)d_in[8];
    const float* W2  = (const float*)d_in[9];
    const float* We2 = (const float*)d_in[10];
    const float* as2 = (const float*)d_in[11];
    const float* ad2 = (const float*)d_in[12];
    const float* ae2 = (const float*)d_in[13];
    const float* b2  = (const float*)d_in[14];
    const float* Wl  = (const float*)d_in[15];
    const float* bl  = (const float*)d_in[16];
    float* out = (float*)d_out;

    float* ws = (float*)d_ws;
    const size_t n = NN;
    float*    cnt    = ws;                 // N
    float*    lsum   = ws + n;             // 4N (becomes loop_attr in place)
    float*    h      = ws + 5 * n;         // 32N
    float*    hs     = ws + 37 * n;        // N
    float*    hd     = ws + 38 * n;        // N
    unsigned* mm     = (unsigned*)(ws + 39 * n); // N
    float*    denom  = ws + 40 * n;        // N
    float*    accum  = ws + 41 * n;        // 32N
    float*    xbuf   = ws + 73 * n;        // 32N
    float*    w4     = ws + 105 * n;       // 8
    float*    logits = ws + 105 * n + 8;   // ET

    dim3 b256(256);
    int gE  = (EE + 255) / 256;
    int gET = (ET + 255) / 256;
    int gN  = (NN + 255) / 256;
    int gN8 = (NN * 8 + 255) / 256;

    // self-loop mean edge_attr + small weight folds
    hipMemsetAsync(ws, 0, 5 * n * sizeof(float), stream);
    k_loop_stats<<<gE, b256, 0, stream>>>(ei, ea, cnt, lsum);
    k_loop_fin<<<gN, b256, 0, stream>>>(lsum, cnt);
    k_small<<<1, 64, 0, stream>>>(We1, ae1, We2, ae2, w4);

    // ---- layer 1 ----
    k_h1<<<gN, b256, 0, stream>>>(x, W1, as1, ad1, h, hs, hd);
    hipMemsetAsync(ws + 39 * n, 0, 34 * n * sizeof(float), stream); // mm, denom, accum
    k_edge_logits<<<gET, b256, 0, stream>>>(ei, ea, lsum, hs, hd, w4, logits, mm);
    k_edge_accum<<<gET, b256, 0, stream>>>(ei, logits, mm, h, denom, accum);
    k_finalize<1><<<gN8, b256, 0, stream>>>(accum, denom, b1, xbuf);

    // ---- layer 2 ----
    k_h2<<<gN, b256, 0, stream>>>(xbuf, W2, as2, ad2, h, hs, hd);
    hipMemsetAsync(ws + 39 * n, 0, 34 * n * sizeof(float), stream);
    k_edge_logits<<<gET, b256, 0, stream>>>(ei, ea, lsum, hs, hd, w4 + 4, logits, mm);
    k_edge_accum<<<gET, b256, 0, stream>>>(ei, logits, mm, h, denom, accum);
    k_finalize<0><<<gN8, b256, 0, stream>>>(accum, denom, b2, xbuf);

    // ---- final linear + relu ----
    k_final<<<gN, b256, 0, stream>>>(xbuf, Wl, bl, out);
}

// Round 2
// 845.129 us; speedup vs baseline: 14.6296x; 14.6296x over previous
//
#include <hip/hip_runtime.h>
#include <hip/hip_fp16.h>

// GAT 2-layer GNN. CSR-gather formulation: build dst-sorted CSR once, then
// per-node wave computes softmax+aggregation with zero atomics in hot loops.
// Per-edge attention scalar prefolded (both layers) into half2 at scatter.

#define NN 100000
#define EE 3200000
#define SLOPE 0.2f

// ---- tiny weight folds: w4_1[4], w4_2[4], vs1[3], vd1[3] (14 floats) ----
__global__ void k_small(const float* __restrict__ We1, const float* __restrict__ ae1,
                        const float* __restrict__ We2, const float* __restrict__ ae2,
                        const float* __restrict__ W1, const float* __restrict__ as1,
                        const float* __restrict__ ad1, float* __restrict__ sml) {
    int t = threadIdx.x;
    if (t < 4) {
        float s = 0.f;
        for (int k = 0; k < 32; k++) s += We1[t * 32 + k] * ae1[k];
        sml[t] = s;
    } else if (t < 8) {
        float s = 0.f;
        for (int k = 0; k < 32; k++) s += We2[(t - 4) * 32 + k] * ae2[k];
        sml[t] = s;
    } else if (t < 11) {
        int i = t - 8;
        float s = 0.f;
        for (int k = 0; k < 32; k++) s += W1[i * 32 + k] * as1[k];
        sml[t] = s;
    } else if (t < 14) {
        int i = t - 11;
        float s = 0.f;
        for (int k = 0; k < 32; k++) s += W1[i * 32 + k] * ad1[k];
        sml[t] = s;
    }
}

__global__ void k_deg(const int* __restrict__ ei, int* __restrict__ deg) {
    int e = blockIdx.x * blockDim.x + threadIdx.x;
    if (e >= EE) return;
    atomicAdd(&deg[ei[EE + e]], 1);
}

// single-block exclusive scan: deg[N] -> rp[N+1], cur[N]
__global__ void k_scan(const int* __restrict__ deg, int* __restrict__ rp, int* __restrict__ cur) {
    __shared__ int sd[1024];
    int t = threadIdx.x;
    const int C = (NN + 1023) / 1024;
    int b = t * C, e2 = min(b + C, NN);
    int sum = 0;
    for (int i = b; i < e2; i++) sum += deg[i];
    sd[t] = sum;
    __syncthreads();
    for (int o = 1; o < 1024; o <<= 1) {
        int v = (t >= o) ? sd[t - o] : 0;
        __syncthreads();
        sd[t] += v;
        __syncthreads();
    }
    int p = sd[t] - sum;  // exclusive prefix
    for (int i = b; i < e2; i++) { rp[i] = p; cur[i] = p; p += deg[i]; }
    if (t == 1023) rp[NN] = sd[1023];
}

// scatter edges into CSR slots; fold ea.(We@a_edge) for both layers into half2
__global__ void k_scatter(const int* __restrict__ ei, const float* __restrict__ ea,
                          const float* __restrict__ sml, int* __restrict__ cur,
                          int* __restrict__ csrc, __half2* __restrict__ ceaw) {
    int e = blockIdx.x * blockDim.x + threadIdx.x;
    if (e >= EE) return;
    int s = ei[e], d = ei[EE + e];
    float4 a = reinterpret_cast<const float4*>(ea)[e];
    float e1 = a.x * sml[0] + a.y * sml[1] + a.z * sml[2] + a.w * sml[3];
    float e2 = a.x * sml[4] + a.y * sml[5] + a.z * sml[6] + a.w * sml[7];
    int p = atomicAdd(&cur[d], 1);
    csrc[p] = s;
    ceaw[p] = __floats2half2_rn(e1, e2);
}

// layer-1 per-node logit dots: hs = x.(W1@a_src), hd = x.(W1@a_dst)
__global__ void k_hs1(const float* __restrict__ x, const float* __restrict__ sml,
                      float* __restrict__ hs, float* __restrict__ hd) {
    int n = blockIdx.x * blockDim.x + threadIdx.x;
    if (n >= NN) return;
    float x0 = x[n * 3], x1 = x[n * 3 + 1], x2 = x[n * 3 + 2];
    hs[n] = x0 * sml[8] + x1 * sml[9] + x2 * sml[10];
    hd[n] = x0 * sml[11] + x1 * sml[12] + x2 * sml[13];
}

// h2 = xbuf @ W2 (N x 32 -> N x 32) + dots with a_src2/a_dst2
__global__ void k_h2(const float* __restrict__ x2, const float* __restrict__ W,
                     const float* __restrict__ as_, const float* __restrict__ ad_,
                     float* __restrict__ h, float* __restrict__ hs, float* __restrict__ hd) {
    __shared__ float sW[1024], sa[32], sdv[32];
    int t = threadIdx.x;
    for (int i = t; i < 1024; i += blockDim.x) sW[i] = W[i];
    if (t < 32) { sa[t] = as_[t]; sdv[t] = ad_[t]; }
    __syncthreads();
    int n = blockIdx.x * blockDim.x + t;
    if (n >= NN) return;
    float xl[32];
    const float4* xp = reinterpret_cast<const float4*>(x2 + (size_t)n * 32);
#pragma unroll
    for (int q = 0; q < 8; q++) {
        float4 v = xp[q];
        xl[q * 4 + 0] = v.x; xl[q * 4 + 1] = v.y; xl[q * 4 + 2] = v.z; xl[q * 4 + 3] = v.w;
    }
    float ss = 0.f, dd = 0.f;
    float* hp = h + (size_t)n * 32;
    for (int q = 0; q < 8; q++) {
        float4 o;
        float* op = (float*)&o;
        for (int j = 0; j < 4; j++) {
            int k = q * 4 + j;
            float acc = 0.f;
#pragma unroll
            for (int i = 0; i < 32; i++) acc += xl[i] * sW[i * 32 + k];
            op[j] = acc;
            ss += acc * sa[k];
            dd += acc * sdv[k];
        }
        reinterpret_cast<float4*>(hp)[q] = o;
    }
    hs[n] = ss; hd[n] = dd;
}

// one wave per node: softmax over incoming edges (+implicit self-loop) and
// weighted aggregation. LAYER=0: recompute h1[src] from x + LDS W1, relu+bias
// write 32-wide. LAYER=1: read h[src], fuse final linear(32->1)+relu.
template <int LAYER>
__global__ void __launch_bounds__(256) k_gather(
    const int* __restrict__ rp, const int* __restrict__ csrc,
    const __half2* __restrict__ ceaw, const float* __restrict__ hsrc,
    const float* __restrict__ W1, const float* __restrict__ hs,
    const float* __restrict__ hd, const float* __restrict__ bias,
    const float* __restrict__ Wl, const float* __restrict__ bl,
    float* __restrict__ out) {
    __shared__ float sW[96];
    if (LAYER == 0) {
        if (threadIdx.x < 96) sW[threadIdx.x] = W1[threadIdx.x];
        __syncthreads();
    }
    int wid = (blockIdx.x * blockDim.x + threadIdx.x) >> 6;
    int lane = threadIdx.x & 63;
    if (wid >= NN) return;
    int n = wid;
    int beg = rp[n], end = rp[n + 1];
    int deg = end - beg;
    float hdn = hd[n];

    // pass 1: max logit + sum of eaw (for self-loop mean attr)
    float mymax = -1e30f, mysum = 0.f;
    for (int j = beg + lane; j < end; j += 64) {
        float2 ew = __half22float2(ceaw[j]);
        float eaw = (LAYER == 0) ? ew.x : ew.y;
        float l = hs[csrc[j]] + hdn + eaw;
        l = (l >= 0.f) ? l : SLOPE * l;
        mymax = fmaxf(mymax, l);
        mysum += eaw;
    }
#pragma unroll
    for (int o = 32; o; o >>= 1) {
        mymax = fmaxf(mymax, __shfl_xor(mymax, o));
        mysum += __shfl_xor(mysum, o);
    }
    float lself = hs[n] + hdn + mysum / fmaxf((float)deg, 1.f);
    lself = (lself >= 0.f) ? lself : SLOPE * lself;
    float m = fmaxf(mymax, lself);

    // pass 2: 8 edge-groups x 8 feature-quads
    int g = lane >> 3, q = lane & 7;
    float ax = 0.f, ay = 0.f, az = 0.f, aw = 0.f, wsum = 0.f;
    for (int j = beg + g; j < end; j += 8) {
        float2 ew = __half22float2(ceaw[j]);
        float eaw = (LAYER == 0) ? ew.x : ew.y;
        int s = csrc[j];
        float l = hs[s] + hdn + eaw;
        l = (l >= 0.f) ? l : SLOPE * l;
        float w = __expf(l - m);
        wsum += w;
        float hx, hy, hz, hw;
        if (LAYER == 0) {
            float x0 = hsrc[s * 3], x1 = hsrc[s * 3 + 1], x2 = hsrc[s * 3 + 2];
            int k = q * 4;
            hx = x0 * sW[k + 0] + x1 * sW[32 + k + 0] + x2 * sW[64 + k + 0];
            hy = x0 * sW[k + 1] + x1 * sW[32 + k + 1] + x2 * sW[64 + k + 1];
            hz = x0 * sW[k + 2] + x1 * sW[32 + k + 2] + x2 * sW[64 + k + 2];
            hw = x0 * sW[k + 3] + x1 * sW[32 + k + 3] + x2 * sW[64 + k + 3];
        } else {
            float4 hv = reinterpret_cast<const float4*>(hsrc + (size_t)s * 32)[q];
            hx = hv.x; hy = hv.y; hz = hv.z; hw = hv.w;
        }
        ax += w * hx; ay += w * hy; az += w * hz; aw += w * hw;
    }
    // implicit self-loop edge
    if (g == (deg & 7)) {
        float w = __expf(lself - m);
        wsum += w;
        float hx, hy, hz, hw;
        if (LAYER == 0) {
            float x0 = hsrc[n * 3], x1 = hsrc[n * 3 + 1], x2 = hsrc[n * 3 + 2];
            int k = q * 4;
            hx = x0 * sW[k + 0] + x1 * sW[32 + k + 0] + x2 * sW[64 + k + 0];
            hy = x0 * sW[k + 1] + x1 * sW[32 + k + 1] + x2 * sW[64 + k + 1];
            hz = x0 * sW[k + 2] + x1 * sW[32 + k + 2] + x2 * sW[64 + k + 2];
            hw = x0 * sW[k + 3] + x1 * sW[32 + k + 3] + x2 * sW[64 + k + 3];
        } else {
            float4 hv = reinterpret_cast<const float4*>(hsrc + (size_t)n * 32)[q];
            hx = hv.x; hy = hv.y; hz = hv.z; hw = hv.w;
        }
        ax += w * hx; ay += w * hy; az += w * hz; aw += w * hw;
    }
    // reduce across the 8 edge-groups (lanes with same q)
#pragma unroll
    for (int o = 8; o < 64; o <<= 1) {
        ax += __shfl_xor(ax, o); ay += __shfl_xor(ay, o);
        az += __shfl_xor(az, o); aw += __shfl_xor(aw, o);
        wsum += __shfl_xor(wsum, o);
    }
    float inv = 1.f / wsum;
    if (LAYER == 0) {
        if (lane < 8) {
            float4 bb = reinterpret_cast<const float4*>(bias)[q];
            float4 o4;
            o4.x = fmaxf(ax * inv + bb.x, 0.f);
            o4.y = fmaxf(ay * inv + bb.y, 0.f);
            o4.z = fmaxf(az * inv + bb.z, 0.f);
            o4.w = fmaxf(aw * inv + bb.w, 0.f);
            reinterpret_cast<float4*>(out + (size_t)n * 32)[q] = o4;
        }
    } else {
        float4 bb = reinterpret_cast<const float4*>(bias)[q];
        float4 wl = reinterpret_cast<const float4*>(Wl)[q];
        float part = (ax * inv + bb.x) * wl.x + (ay * inv + bb.y) * wl.y +
                     (az * inv + bb.z) * wl.z + (aw * inv + bb.w) * wl.w;
        part += __shfl_xor(part, 1);
        part += __shfl_xor(part, 2);
        part += __shfl_xor(part, 4);
        if (lane == 0) out[n] = fmaxf(part + bl[0], 0.f);
    }
}

extern "C" void kernel_launch(void* const* d_in, const int* in_sizes, int n_in,
                              void* d_out, int out_size, void* d_ws, size_t ws_size,
                              hipStream_t stream) {
    const float* x   = (const float*)d_in[0];
    const int*   ei  = (const int*)d_in[1];
    const float* ea  = (const float*)d_in[2];
    const float* W1  = (const float*)d_in[3];
    const float* We1 = (const float*)d_in[4];
    const float* as1 = (const float*)d_in[5];
    const float* ad1 = (const float*)d_in[6];
    const float* ae1 = (const float*)d_in[7];
    const float* b1  = (const float*)d_in[8];
    const float* W2  = (const float*)d_in[9];
    const float* We2 = (const float*)d_in[10];
    const float* as2 = (const float*)d_in[11];
    const float* ad2 = (const float*)d_in[12];
    const float* ae2 = (const float*)d_in[13];
    const float* b2  = (const float*)d_in[14];
    const float* Wl  = (const float*)d_in[15];
    const float* bl  = (const float*)d_in[16];
    float* out = (float*)d_out;

    const size_t n = NN, E = EE;
    float* ws = (float*)d_ws;
    int*     rp   = (int*)ws;                       // n+1 (pad n+4)
    int*     cur  = (int*)ws + n + 4;               // n   (also deg)
    float*   hs   = ws + 2 * n + 4;                 // n
    float*   hd   = ws + 3 * n + 4;                 // n
    float*   sml  = ws + 4 * n + 4;                 // 16
    int*     csrc = (int*)(ws + 4 * n + 20);        // E
    __half2* ceaw = (__half2*)(ws + 4 * n + 20 + E);// E (4B each)
    float*   h    = ws + 4 * n + 20 + 2 * E;        // 32n
    float*   xbuf = ws + 36 * n + 20 + 2 * E;       // 32n

    dim3 b256(256);
    int gE = (EE + 255) / 256;
    int gN = (NN + 255) / 256;
    int gG = (NN * 64 + 255) / 256;

    // CSR build
    hipMemsetAsync(cur, 0, n * sizeof(int), stream);  // cur doubles as deg
    k_small<<<1, 64, 0, stream>>>(We1, ae1, We2, ae2, W1, as1, ad1, sml);
    k_deg<<<gE, b256, 0, stream>>>(ei, cur);
    k_scan<<<1, 1024, 0, stream>>>(cur, rp, cur);  // reads deg, rewrites cur
    k_scatter<<<gE, b256, 0, stream>>>(ei, ea, sml, cur, csrc, ceaw);

    // layer 1 (h1 recomputed on the fly from x)
    k_hs1<<<gN, b256, 0, stream>>>(x, sml, hs, hd);
    k_gather<0><<<gG, b256, 0, stream>>>(rp, csrc, ceaw, x, W1, hs, hd, b1,
                                         nullptr, nullptr, xbuf);

    // layer 2 (+ fused final linear + relu)
    k_h2<<<gN, b256, 0, stream>>>(xbuf, W2, as2, ad2, h, hs, hd);
    k_gather<1><<<gG, b256, 0, stream>>>(rp, csrc, ceaw, h, nullptr, hs, hd, b2,
                                         Wl, bl, out);
}

// Round 4
// 626.797 us; speedup vs baseline: 19.7254x; 1.3483x over previous
//
#include <hip/hip_runtime.h>
#include <hip/hip_fp16.h>

// GAT 2-layer GNN. CSR-gather formulation: build dst-sorted CSR once, then
// per-node wave computes softmax+aggregation with zero atomics in hot loops.
// R3: hierarchical 3-stage scan replaces the single-block scan (233us -> ~15us).
// (Resubmit — R3 bench hit GPUAcquisitionTimeout, kernel never ran.)

#define NN 100000
#define EE 3200000
#define SLOPE 0.2f
#define SB 1024
#define SNB ((NN + SB - 1) / SB)   // 98 blocks

// ---- tiny weight folds: w4_1[4], w4_2[4], vs1[3], vd1[3] (14 floats) ----
__global__ void k_small(const float* __restrict__ We1, const float* __restrict__ ae1,
                        const float* __restrict__ We2, const float* __restrict__ ae2,
                        const float* __restrict__ W1, const float* __restrict__ as1,
                        const float* __restrict__ ad1, float* __restrict__ sml) {
    int t = threadIdx.x;
    if (t < 4) {
        float s = 0.f;
        for (int k = 0; k < 32; k++) s += We1[t * 32 + k] * ae1[k];
        sml[t] = s;
    } else if (t < 8) {
        float s = 0.f;
        for (int k = 0; k < 32; k++) s += We2[(t - 4) * 32 + k] * ae2[k];
        sml[t] = s;
    } else if (t < 11) {
        int i = t - 8;
        float s = 0.f;
        for (int k = 0; k < 32; k++) s += W1[i * 32 + k] * as1[k];
        sml[t] = s;
    } else if (t < 14) {
        int i = t - 11;
        float s = 0.f;
        for (int k = 0; k < 32; k++) s += W1[i * 32 + k] * ad1[k];
        sml[t] = s;
    }
}

__global__ void k_deg(const int* __restrict__ ei, int* __restrict__ deg) {
    int e = blockIdx.x * blockDim.x + threadIdx.x;
    if (e >= EE) return;
    atomicAdd(&deg[ei[EE + e]], 1);
}

// stage 1: per-block LDS scan; loc[i] = exclusive prefix within block, bsum[b] = block total
__global__ void k_scan1(const int* __restrict__ deg, int* __restrict__ loc,
                        int* __restrict__ bsum) {
    __shared__ int sd[SB];
    int t = threadIdx.x;
    int i = blockIdx.x * SB + t;
    int v = (i < NN) ? deg[i] : 0;
    sd[t] = v;
    __syncthreads();
    for (int o = 1; o < SB; o <<= 1) {
        int u = (t >= o) ? sd[t - o] : 0;
        __syncthreads();
        sd[t] += u;
        __syncthreads();
    }
    if (i < NN) loc[i] = sd[t] - v;
    if (t == SB - 1) bsum[blockIdx.x] = sd[t];
}

// stage 2: single small block scans the block sums in place (-> exclusive offsets)
__global__ void k_scan2(int* __restrict__ bsum) {
    __shared__ int sd[128];
    int t = threadIdx.x;
    int v = (t < SNB) ? bsum[t] : 0;
    sd[t] = v;
    __syncthreads();
    for (int o = 1; o < 128; o <<= 1) {
        int u = (t >= o) ? sd[t - o] : 0;
        __syncthreads();
        sd[t] += u;
        __syncthreads();
    }
    if (t < SNB) bsum[t] = sd[t] - v;
}

// stage 3: rp[i] = loc[i] + bsum[i/SB]; cur mirrors rp; rp[NN] = EE
__global__ void k_scan3(const int* __restrict__ loc, const int* __restrict__ bsum,
                        int* __restrict__ rp, int* __restrict__ cur) {
    int i = blockIdx.x * blockDim.x + threadIdx.x;
    if (i > NN) return;
    if (i == NN) { rp[NN] = EE; return; }
    int p = loc[i] + bsum[i / SB];
    rp[i] = p;
    cur[i] = p;
}

// scatter edges into CSR slots; fold ea.(We@a_edge) for both layers into half2
__global__ void k_scatter(const int* __restrict__ ei, const float* __restrict__ ea,
                          const float* __restrict__ sml, int* __restrict__ cur,
                          int* __restrict__ csrc, __half2* __restrict__ ceaw) {
    int e = blockIdx.x * blockDim.x + threadIdx.x;
    if (e >= EE) return;
    int s = ei[e], d = ei[EE + e];
    float4 a = reinterpret_cast<const float4*>(ea)[e];
    float e1 = a.x * sml[0] + a.y * sml[1] + a.z * sml[2] + a.w * sml[3];
    float e2 = a.x * sml[4] + a.y * sml[5] + a.z * sml[6] + a.w * sml[7];
    int p = atomicAdd(&cur[d], 1);
    csrc[p] = s;
    ceaw[p] = __floats2half2_rn(e1, e2);
}

// layer-1 per-node logit dots: hs = x.(W1@a_src), hd = x.(W1@a_dst)
__global__ void k_hs1(const float* __restrict__ x, const float* __restrict__ sml,
                      float* __restrict__ hs, float* __restrict__ hd) {
    int n = blockIdx.x * blockDim.x + threadIdx.x;
    if (n >= NN) return;
    float x0 = x[n * 3], x1 = x[n * 3 + 1], x2 = x[n * 3 + 2];
    hs[n] = x0 * sml[8] + x1 * sml[9] + x2 * sml[10];
    hd[n] = x0 * sml[11] + x1 * sml[12] + x2 * sml[13];
}

// h2 = xbuf @ W2 (N x 32 -> N x 32) + dots with a_src2/a_dst2
__global__ void k_h2(const float* __restrict__ x2, const float* __restrict__ W,
                     const float* __restrict__ as_, const float* __restrict__ ad_,
                     float* __restrict__ h, float* __restrict__ hs, float* __restrict__ hd) {
    __shared__ float sW[1024], sa[32], sdv[32];
    int t = threadIdx.x;
    for (int i = t; i < 1024; i += blockDim.x) sW[i] = W[i];
    if (t < 32) { sa[t] = as_[t]; sdv[t] = ad_[t]; }
    __syncthreads();
    int n = blockIdx.x * blockDim.x + t;
    if (n >= NN) return;
    float xl[32];
    const float4* xp = reinterpret_cast<const float4*>(x2 + (size_t)n * 32);
#pragma unroll
    for (int q = 0; q < 8; q++) {
        float4 v = xp[q];
        xl[q * 4 + 0] = v.x; xl[q * 4 + 1] = v.y; xl[q * 4 + 2] = v.z; xl[q * 4 + 3] = v.w;
    }
    float ss = 0.f, dd = 0.f;
    float* hp = h + (size_t)n * 32;
    for (int q = 0; q < 8; q++) {
        float4 o;
        float* op = (float*)&o;
        for (int j = 0; j < 4; j++) {
            int k = q * 4 + j;
            float acc = 0.f;
#pragma unroll
            for (int i = 0; i < 32; i++) acc += xl[i] * sW[i * 32 + k];
            op[j] = acc;
            ss += acc * sa[k];
            dd += acc * sdv[k];
        }
        reinterpret_cast<float4*>(hp)[q] = o;
    }
    hs[n] = ss; hd[n] = dd;
}

// one wave per node: softmax over incoming edges (+implicit self-loop) and
// weighted aggregation. LAYER=0: recompute h1[src] from x + LDS W1, relu+bias
// write 32-wide. LAYER=1: read h[src], fuse final linear(32->1)+relu.
template <int LAYER>
__global__ void __launch_bounds__(256) k_gather(
    const int* __restrict__ rp, const int* __restrict__ csrc,
    const __half2* __restrict__ ceaw, const float* __restrict__ hsrc,
    const float* __restrict__ W1, const float* __restrict__ hs,
    const float* __restrict__ hd, const float* __restrict__ bias,
    const float* __restrict__ Wl, const float* __restrict__ bl,
    float* __restrict__ out) {
    __shared__ float sW[96];
    if (LAYER == 0) {
        if (threadIdx.x < 96) sW[threadIdx.x] = W1[threadIdx.x];
        __syncthreads();
    }
    int wid = (blockIdx.x * blockDim.x + threadIdx.x) >> 6;
    int lane = threadIdx.x & 63;
    if (wid >= NN) return;
    int n = wid;
    int beg = rp[n], end = rp[n + 1];
    int deg = end - beg;
    float hdn = hd[n];

    // pass 1: max logit + sum of eaw (for self-loop mean attr)
    float mymax = -1e30f, mysum = 0.f;
    for (int j = beg + lane; j < end; j += 64) {
        float2 ew = __half22float2(ceaw[j]);
        float eaw = (LAYER == 0) ? ew.x : ew.y;
        float l = hs[csrc[j]] + hdn + eaw;
        l = (l >= 0.f) ? l : SLOPE * l;
        mymax = fmaxf(mymax, l);
        mysum += eaw;
    }
#pragma unroll
    for (int o = 32; o; o >>= 1) {
        mymax = fmaxf(mymax, __shfl_xor(mymax, o));
        mysum += __shfl_xor(mysum, o);
    }
    float lself = hs[n] + hdn + mysum / fmaxf((float)deg, 1.f);
    lself = (lself >= 0.f) ? lself : SLOPE * lself;
    float m = fmaxf(mymax, lself);

    // pass 2: 8 edge-groups x 8 feature-quads
    int g = lane >> 3, q = lane & 7;
    float ax = 0.f, ay = 0.f, az = 0.f, aw = 0.f, wsum = 0.f;
    for (int j = beg + g; j < end; j += 8) {
        float2 ew = __half22float2(ceaw[j]);
        float eaw = (LAYER == 0) ? ew.x : ew.y;
        int s = csrc[j];
        float l = hs[s] + hdn + eaw;
        l = (l >= 0.f) ? l : SLOPE * l;
        float w = __expf(l - m);
        wsum += w;
        float hx, hy, hz, hw;
        if (LAYER == 0) {
            float x0 = hsrc[s * 3], x1 = hsrc[s * 3 + 1], x2 = hsrc[s * 3 + 2];
            int k = q * 4;
            hx = x0 * sW[k + 0] + x1 * sW[32 + k + 0] + x2 * sW[64 + k + 0];
            hy = x0 * sW[k + 1] + x1 * sW[32 + k + 1] + x2 * sW[64 + k + 1];
            hz = x0 * sW[k + 2] + x1 * sW[32 + k + 2] + x2 * sW[64 + k + 2];
            hw = x0 * sW[k + 3] + x1 * sW[32 + k + 3] + x2 * sW[64 + k + 3];
        } else {
            float4 hv = reinterpret_cast<const float4*>(hsrc + (size_t)s * 32)[q];
            hx = hv.x; hy = hv.y; hz = hv.z; hw = hv.w;
        }
        ax += w * hx; ay += w * hy; az += w * hz; aw += w * hw;
    }
    // implicit self-loop edge
    if (g == (deg & 7)) {
        float w = __expf(lself - m);
        wsum += w;
        float hx, hy, hz, hw;
        if (LAYER == 0) {
            float x0 = hsrc[n * 3], x1 = hsrc[n * 3 + 1], x2 = hsrc[n * 3 + 2];
            int k = q * 4;
            hx = x0 * sW[k + 0] + x1 * sW[32 + k + 0] + x2 * sW[64 + k + 0];
            hy = x0 * sW[k + 1] + x1 * sW[32 + k + 1] + x2 * sW[64 + k + 1];
            hz = x0 * sW[k + 2] + x1 * sW[32 + k + 2] + x2 * sW[64 + k + 2];
            hw = x0 * sW[k + 3] + x1 * sW[32 + k + 3] + x2 * sW[64 + k + 3];
        } else {
            float4 hv = reinterpret_cast<const float4*>(hsrc + (size_t)n * 32)[q];
            hx = hv.x; hy = hv.y; hz = hv.z; hw = hv.w;
        }
        ax += w * hx; ay += w * hy; az += w * hz; aw += w * hw;
    }
    // reduce across the 8 edge-groups (lanes with same q)
#pragma unroll
    for (int o = 8; o < 64; o <<= 1) {
        ax += __shfl_xor(ax, o); ay += __shfl_xor(ay, o);
        az += __shfl_xor(az, o); aw += __shfl_xor(aw, o);
        wsum += __shfl_xor(wsum, o);
    }
    float inv = 1.f / wsum;
    if (LAYER == 0) {
        if (lane < 8) {
            float4 bb = reinterpret_cast<const float4*>(bias)[q];
            float4 o4;
            o4.x = fmaxf(ax * inv + bb.x, 0.f);
            o4.y = fmaxf(ay * inv + bb.y, 0.f);
            o4.z = fmaxf(az * inv + bb.z, 0.f);
            o4.w = fmaxf(aw * inv + bb.w, 0.f);
            reinterpret_cast<float4*>(out + (size_t)n * 32)[q] = o4;
        }
    } else {
        float4 bb = reinterpret_cast<const float4*>(bias)[q];
        float4 wl = reinterpret_cast<const float4*>(Wl)[q];
        float part = (ax * inv + bb.x) * wl.x + (ay * inv + bb.y) * wl.y +
                     (az * inv + bb.z) * wl.z + (aw * inv + bb.w) * wl.w;
        part += __shfl_xor(part, 1);
        part += __shfl_xor(part, 2);
        part += __shfl_xor(part, 4);
        if (lane == 0) out[n] = fmaxf(part + bl[0], 0.f);
    }
}

extern "C" void kernel_launch(void* const* d_in, const int* in_sizes, int n_in,
                              void* d_out, int out_size, void* d_ws, size_t ws_size,
                              hipStream_t stream) {
    const float* x   = (const float*)d_in[0];
    const int*   ei  = (const int*)d_in[1];
    const float* ea  = (const float*)d_in[2];
    const float* W1  = (const float*)d_in[3];
    const float* We1 = (const float*)d_in[4];
    const float* as1 = (const float*)d_in[5];
    const float* ad1 = (const float*)d_in[6];
    const float* ae1 = (const float*)d_in[7];
    const float* b1  = (const float*)d_in[8];
    const float* W2  = (const float*)d_in[9];
    const float* We2 = (const float*)d_in[10];
    const float* as2 = (const float*)d_in[11];
    const float* ad2 = (const float*)d_in[12];
    const float* ae2 = (const float*)d_in[13];
    const float* b2  = (const float*)d_in[14];
    const float* Wl  = (const float*)d_in[15];
    const float* bl  = (const float*)d_in[16];
    float* out = (float*)d_out;

    const size_t n = NN, E = EE;
    float* ws = (float*)d_ws;
    int*     rp   = (int*)ws;                        // n+1 (pad to n+4)
    int*     deg  = (int*)ws + n + 4;                // n
    int*     cur  = (int*)ws + 2 * n + 4;            // n
    int*     loc  = (int*)ws + 3 * n + 4;            // n
    int*     bsum = (int*)ws + 4 * n + 4;            // 128
    float*   hs   = ws + 4 * n + 132;                // n
    float*   hd   = ws + 5 * n + 132;                // n
    float*   sml  = ws + 6 * n + 132;                // 16
    int*     csrc = (int*)(ws + 6 * n + 148);        // E
    __half2* ceaw = (__half2*)(ws + 6 * n + 148 + E);// E (4B each)
    float*   h    = ws + 6 * n + 148 + 2 * E;        // 32n
    float*   xbuf = ws + 38 * n + 148 + 2 * E;       // 32n

    dim3 b256(256);
    int gE  = (EE + 255) / 256;
    int gN  = (NN + 255) / 256;
    int gN1 = (NN + 256) / 256;   // covers NN+1 for rp[NN]
    int gG  = (NN * 64 + 255) / 256;

    // CSR build
    hipMemsetAsync(deg, 0, n * sizeof(int), stream);
    k_small<<<1, 64, 0, stream>>>(We1, ae1, We2, ae2, W1, as1, ad1, sml);
    k_deg<<<gE, b256, 0, stream>>>(ei, deg);
    k_scan1<<<SNB, SB, 0, stream>>>(deg, loc, bsum);
    k_scan2<<<1, 128, 0, stream>>>(bsum);
    k_scan3<<<gN1, b256, 0, stream>>>(loc, bsum, rp, cur);
    k_scatter<<<gE, b256, 0, stream>>>(ei, ea, sml, cur, csrc, ceaw);

    // layer 1 (h1 recomputed on the fly from x)
    k_hs1<<<gN, b256, 0, stream>>>(x, sml, hs, hd);
    k_gather<0><<<gG, b256, 0, stream>>>(rp, csrc, ceaw, x, W1, hs, hd, b1,
                                         nullptr, nullptr, xbuf);

    // layer 2 (+ fused final linear + relu)
    k_h2<<<gN, b256, 0, stream>>>(xbuf, W2, as2, ad2, h, hs, hd);
    k_gather<1><<<gG, b256, 0, stream>>>(rp, csrc, ceaw, h, nullptr, hs, hd, b2,
                                         Wl, bl, out);
}

// Round 8
// 622.282 us; speedup vs baseline: 19.8686x; 1.0073x over previous
//
#include <hip/hip_runtime.h>
#include <hip/hip_fp16.h>

// GAT 2-layer GNN. CSR-gather formulation.
// R5b: pack CSR payload into one int2 {src, half2(eaw1,eaw2)} -> single 8B
// scatter store per edge (halves random-write line amplification); fuse
// k_hs1 into k_scan3. (Resubmit x2 — R6/R7 benches hit GPUAcquisitionTimeout.)

#define NN 100000
#define EE 3200000
#define SLOPE 0.2f
#define SB 1024
#define SNB ((NN + SB - 1) / SB)   // 98 blocks

// ---- tiny weight folds: w4_1[4], w4_2[4], vs1[3], vd1[3] (14 floats) ----
__global__ void k_small(const float* __restrict__ We1, const float* __restrict__ ae1,
                        const float* __restrict__ We2, const float* __restrict__ ae2,
                        const float* __restrict__ W1, const float* __restrict__ as1,
                        const float* __restrict__ ad1, float* __restrict__ sml) {
    int t = threadIdx.x;
    if (t < 4) {
        float s = 0.f;
        for (int k = 0; k < 32; k++) s += We1[t * 32 + k] * ae1[k];
        sml[t] = s;
    } else if (t < 8) {
        float s = 0.f;
        for (int k = 0; k < 32; k++) s += We2[(t - 4) * 32 + k] * ae2[k];
        sml[t] = s;
    } else if (t < 11) {
        int i = t - 8;
        float s = 0.f;
        for (int k = 0; k < 32; k++) s += W1[i * 32 + k] * as1[k];
        sml[t] = s;
    } else if (t < 14) {
        int i = t - 11;
        float s = 0.f;
        for (int k = 0; k < 32; k++) s += W1[i * 32 + k] * ad1[k];
        sml[t] = s;
    }
}

__global__ void k_deg(const int* __restrict__ ei, int* __restrict__ deg) {
    int e = blockIdx.x * blockDim.x + threadIdx.x;
    if (e >= EE) return;
    atomicAdd(&deg[ei[EE + e]], 1);
}

// stage 1: per-block LDS scan
__global__ void k_scan1(const int* __restrict__ deg, int* __restrict__ loc,
                        int* __restrict__ bsum) {
    __shared__ int sd[SB];
    int t = threadIdx.x;
    int i = blockIdx.x * SB + t;
    int v = (i < NN) ? deg[i] : 0;
    sd[t] = v;
    __syncthreads();
    for (int o = 1; o < SB; o <<= 1) {
        int u = (t >= o) ? sd[t - o] : 0;
        __syncthreads();
        sd[t] += u;
        __syncthreads();
    }
    if (i < NN) loc[i] = sd[t] - v;
    if (t == SB - 1) bsum[blockIdx.x] = sd[t];
}

// stage 2: single small block scans the block sums in place
__global__ void k_scan2(int* __restrict__ bsum) {
    __shared__ int sd[128];
    int t = threadIdx.x;
    int v = (t < SNB) ? bsum[t] : 0;
    sd[t] = v;
    __syncthreads();
    for (int o = 1; o < 128; o <<= 1) {
        int u = (t >= o) ? sd[t - o] : 0;
        __syncthreads();
        sd[t] += u;
        __syncthreads();
    }
    if (t < SNB) bsum[t] = sd[t] - v;
}

// stage 3: rp/cur = combined prefix; fused layer-1 logit dots hs/hd
__global__ void k_scan3(const int* __restrict__ loc, const int* __restrict__ bsum,
                        int* __restrict__ rp, int* __restrict__ cur,
                        const float* __restrict__ x, const float* __restrict__ sml,
                        float* __restrict__ hs, float* __restrict__ hd) {
    int i = blockIdx.x * blockDim.x + threadIdx.x;
    if (i > NN) return;
    if (i == NN) { rp[NN] = EE; return; }
    int p = loc[i] + bsum[i / SB];
    rp[i] = p;
    cur[i] = p;
    float x0 = x[i * 3], x1 = x[i * 3 + 1], x2 = x[i * 3 + 2];
    hs[i] = x0 * sml[8] + x1 * sml[9] + x2 * sml[10];
    hd[i] = x0 * sml[11] + x1 * sml[12] + x2 * sml[13];
}

// scatter: single 8B record per edge {src, half2(eaw1, eaw2)}
__global__ void k_scatter(const int* __restrict__ ei, const float* __restrict__ ea,
                          const float* __restrict__ sml, int* __restrict__ cur,
                          int2* __restrict__ cpack) {
    int e = blockIdx.x * blockDim.x + threadIdx.x;
    if (e >= EE) return;
    int s = ei[e], d = ei[EE + e];
    float4 a = reinterpret_cast<const float4*>(ea)[e];
    float e1 = a.x * sml[0] + a.y * sml[1] + a.z * sml[2] + a.w * sml[3];
    float e2 = a.x * sml[4] + a.y * sml[5] + a.z * sml[6] + a.w * sml[7];
    __half2 hv = __floats2half2_rn(e1, e2);
    int2 rec;
    rec.x = s;
    rec.y = *reinterpret_cast<int*>(&hv);
    int p = atomicAdd(&cur[d], 1);
    cpack[p] = rec;
}

// h2 = xbuf @ W2 (N x 32 -> N x 32) + dots with a_src2/a_dst2
__global__ void k_h2(const float* __restrict__ x2, const float* __restrict__ W,
                     const float* __restrict__ as_, const float* __restrict__ ad_,
                     float* __restrict__ h, float* __restrict__ hs, float* __restrict__ hd) {
    __shared__ float sW[1024], sa[32], sdv[32];
    int t = threadIdx.x;
    for (int i = t; i < 1024; i += blockDim.x) sW[i] = W[i];
    if (t < 32) { sa[t] = as_[t]; sdv[t] = ad_[t]; }
    __syncthreads();
    int n = blockIdx.x * blockDim.x + t;
    if (n >= NN) return;
    float xl[32];
    const float4* xp = reinterpret_cast<const float4*>(x2 + (size_t)n * 32);
#pragma unroll
    for (int q = 0; q < 8; q++) {
        float4 v = xp[q];
        xl[q * 4 + 0] = v.x; xl[q * 4 + 1] = v.y; xl[q * 4 + 2] = v.z; xl[q * 4 + 3] = v.w;
    }
    float ss = 0.f, dd = 0.f;
    float* hp = h + (size_t)n * 32;
    for (int q = 0; q < 8; q++) {
        float4 o;
        float* op = (float*)&o;
        for (int j = 0; j < 4; j++) {
            int k = q * 4 + j;
            float acc = 0.f;
#pragma unroll
            for (int i = 0; i < 32; i++) acc += xl[i] * sW[i * 32 + k];
            op[j] = acc;
            ss += acc * sa[k];
            dd += acc * sdv[k];
        }
        reinterpret_cast<float4*>(hp)[q] = o;
    }
    hs[n] = ss; hd[n] = dd;
}

// one wave per node: softmax + aggregation. LAYER=0: recompute h1[src] from x;
// LAYER=1: read h[src], fuse final linear(32->1)+relu.
template <int LAYER>
__global__ void __launch_bounds__(256) k_gather(
    const int* __restrict__ rp, const int2* __restrict__ cpack,
    const float* __restrict__ hsrc,
    const float* __restrict__ W1, const float* __restrict__ hs,
    const float* __restrict__ hd, const float* __restrict__ bias,
    const float* __restrict__ Wl, const float* __restrict__ bl,
    float* __restrict__ out) {
    __shared__ float sW[96];
    if (LAYER == 0) {
        if (threadIdx.x < 96) sW[threadIdx.x] = W1[threadIdx.x];
        __syncthreads();
    }
    int wid = (blockIdx.x * blockDim.x + threadIdx.x) >> 6;
    int lane = threadIdx.x & 63;
    if (wid >= NN) return;
    int n = wid;
    int beg = rp[n], end = rp[n + 1];
    int deg = end - beg;
    float hdn = hd[n];

    // pass 1: max logit + sum of eaw (for self-loop mean attr)
    float mymax = -1e30f, mysum = 0.f;
    for (int j = beg + lane; j < end; j += 64) {
        int2 cp = cpack[j];
        __half2 hv = *reinterpret_cast<__half2*>(&cp.y);
        float2 ew = __half22float2(hv);
        float eaw = (LAYER == 0) ? ew.x : ew.y;
        float l = hs[cp.x] + hdn + eaw;
        l = (l >= 0.f) ? l : SLOPE * l;
        mymax = fmaxf(mymax, l);
        mysum += eaw;
    }
#pragma unroll
    for (int o = 32; o; o >>= 1) {
        mymax = fmaxf(mymax, __shfl_xor(mymax, o));
        mysum += __shfl_xor(mysum, o);
    }
    float lself = hs[n] + hdn + mysum / fmaxf((float)deg, 1.f);
    lself = (lself >= 0.f) ? lself : SLOPE * lself;
    float m = fmaxf(mymax, lself);

    // pass 2: 8 edge-groups x 8 feature-quads
    int g = lane >> 3, q = lane & 7;
    float ax = 0.f, ay = 0.f, az = 0.f, aw = 0.f, wsum = 0.f;
    for (int j = beg + g; j < end; j += 8) {
        int2 cp = cpack[j];
        __half2 hv2 = *reinterpret_cast<__half2*>(&cp.y);
        float2 ew = __half22float2(hv2);
        float eaw = (LAYER == 0) ? ew.x : ew.y;
        int s = cp.x;
        float l = hs[s] + hdn + eaw;
        l = (l >= 0.f) ? l : SLOPE * l;
        float w = __expf(l - m);
        wsum += w;
        float hx, hy, hz, hw;
        if (LAYER == 0) {
            float x0 = hsrc[s * 3], x1 = hsrc[s * 3 + 1], x2 = hsrc[s * 3 + 2];
            int k = q * 4;
            hx = x0 * sW[k + 0] + x1 * sW[32 + k + 0] + x2 * sW[64 + k + 0];
            hy = x0 * sW[k + 1] + x1 * sW[32 + k + 1] + x2 * sW[64 + k + 1];
            hz = x0 * sW[k + 2] + x1 * sW[32 + k + 2] + x2 * sW[64 + k + 2];
            hw = x0 * sW[k + 3] + x1 * sW[32 + k + 3] + x2 * sW[64 + k + 3];
        } else {
            float4 hv4 = reinterpret_cast<const float4*>(hsrc + (size_t)s * 32)[q];
            hx = hv4.x; hy = hv4.y; hz = hv4.z; hw = hv4.w;
        }
        ax += w * hx; ay += w * hy; az += w * hz; aw += w * hw;
    }
    // implicit self-loop edge
    if (g == (deg & 7)) {
        float w = __expf(lself - m);
        wsum += w;
        float hx, hy, hz, hw;
        if (LAYER == 0) {
            float x0 = hsrc[n * 3], x1 = hsrc[n * 3 + 1], x2 = hsrc[n * 3 + 2];
            int k = q * 4;
            hx = x0 * sW[k + 0] + x1 * sW[32 + k + 0] + x2 * sW[64 + k + 0];
            hy = x0 * sW[k + 1] + x1 * sW[32 + k + 1] + x2 * sW[64 + k + 1];
            hz = x0 * sW[k + 2] + x1 * sW[32 + k + 2] + x2 * sW[64 + k + 2];
            hw = x0 * sW[k + 3] + x1 * sW[32 + k + 3] + x2 * sW[64 + k + 3];
        } else {
            float4 hv4 = reinterpret_cast<const float4*>(hsrc + (size_t)n * 32)[q];
            hx = hv4.x; hy = hv4.y; hz = hv4.z; hw = hv4.w;
        }
        ax += w * hx; ay += w * hy; az += w * hz; aw += w * hw;
    }
    // reduce across the 8 edge-groups (lanes with same q)
#pragma unroll
    for (int o = 8; o < 64; o <<= 1) {
        ax += __shfl_xor(ax, o); ay += __shfl_xor(ay, o);
        az += __shfl_xor(az, o); aw += __shfl_xor(aw, o);
        wsum += __shfl_xor(wsum, o);
    }
    float inv = 1.f / wsum;
    if (LAYER == 0) {
        if (lane < 8) {
            float4 bb = reinterpret_cast<const float4*>(bias)[q];
            float4 o4;
            o4.x = fmaxf(ax * inv + bb.x, 0.f);
            o4.y = fmaxf(ay * inv + bb.y, 0.f);
            o4.z = fmaxf(az * inv + bb.z, 0.f);
            o4.w = fmaxf(aw * inv + bb.w, 0.f);
            reinterpret_cast<float4*>(out + (size_t)n * 32)[q] = o4;
        }
    } else {
        float4 bb = reinterpret_cast<const float4*>(bias)[q];
        float4 wl = reinterpret_cast<const float4*>(Wl)[q];
        float part = (ax * inv + bb.x) * wl.x + (ay * inv + bb.y) * wl.y +
                     (az * inv + bb.z) * wl.z + (aw * inv + bb.w) * wl.w;
        part += __shfl_xor(part, 1);
        part += __shfl_xor(part, 2);
        part += __shfl_xor(part, 4);
        if (lane == 0) out[n] = fmaxf(part + bl[0], 0.f);
    }
}

extern "C" void kernel_launch(void* const* d_in, const int* in_sizes, int n_in,
                              void* d_out, int out_size, void* d_ws, size_t ws_size,
                              hipStream_t stream) {
    const float* x   = (const float*)d_in[0];
    const int*   ei  = (const int*)d_in[1];
    const float* ea  = (const float*)d_in[2];
    const float* W1  = (const float*)d_in[3];
    const float* We1 = (const float*)d_in[4];
    const float* as1 = (const float*)d_in[5];
    const float* ad1 = (const float*)d_in[6];
    const float* ae1 = (const float*)d_in[7];
    const float* b1  = (const float*)d_in[8];
    const float* W2  = (const float*)d_in[9];
    const float* We2 = (const float*)d_in[10];
    const float* as2 = (const float*)d_in[11];
    const float* ad2 = (const float*)d_in[12];
    const float* ae2 = (const float*)d_in[13];
    const float* b2  = (const float*)d_in[14];
    const float* Wl  = (const float*)d_in[15];
    const float* bl  = (const float*)d_in[16];
    float* out = (float*)d_out;

    const size_t n = NN, E = EE;
    float* ws = (float*)d_ws;
    int*   rp    = (int*)ws;                         // n+1 (pad to n+4)
    int*   deg   = (int*)ws + n + 4;                 // n
    int*   cur   = (int*)ws + 2 * n + 4;             // n
    int*   loc   = (int*)ws + 3 * n + 4;             // n
    int*   bsum  = (int*)ws + 4 * n + 4;             // 128
    float* hs    = ws + 4 * n + 132;                 // n
    float* hd    = ws + 5 * n + 132;                 // n
    float* sml   = ws + 6 * n + 132;                 // 16
    int2*  cpack = (int2*)(ws + 6 * n + 148);        // E (8B each)
    float* h     = ws + 6 * n + 148 + 2 * E;         // 32n
    float* xbuf  = ws + 38 * n + 148 + 2 * E;        // 32n

    dim3 b256(256);
    int gE  = (EE + 255) / 256;
    int gN  = (NN + 255) / 256;
    int gN1 = (NN + 256) / 256;   // covers NN+1
    int gG  = (NN * 64 + 255) / 256;

    // CSR build
    hipMemsetAsync(deg, 0, n * sizeof(int), stream);
    k_small<<<1, 64, 0, stream>>>(We1, ae1, We2, ae2, W1, as1, ad1, sml);
    k_deg<<<gE, b256, 0, stream>>>(ei, deg);
    k_scan1<<<SNB, SB, 0, stream>>>(deg, loc, bsum);
    k_scan2<<<1, 128, 0, stream>>>(bsum);
    k_scan3<<<gN1, b256, 0, stream>>>(loc, bsum, rp, cur, x, sml, hs, hd);
    k_scatter<<<gE, b256, 0, stream>>>(ei, ea, sml, cur, cpack);

    // layer 1 (h1 recomputed on the fly from x)
    k_gather<0><<<gG, b256, 0, stream>>>(rp, cpack, x, W1, hs, hd, b1,
                                         nullptr, nullptr, xbuf);

    // layer 2 (+ fused final linear + relu)
    k_h2<<<gN, b256, 0, stream>>>(xbuf, W2, as2, ad2, h, hs, hd);
    k_gather<1><<<gG, b256, 0, stream>>>(rp, cpack, h, nullptr, hs, hd, b2,
                                         Wl, bl, out);
}